// Round 8
// baseline (62396.344 us; speedup 1.0000x reference)
//
#include <hip/hip_runtime.h>
#include <cstdint>

typedef __bf16 bf16x8 __attribute__((ext_vector_type(8)));
typedef float  f32x4  __attribute__((ext_vector_type(4)));

union U4B { uint4 u; bf16x8 b; };
__device__ __forceinline__ bf16x8 as_bf(uint4 u) { U4B x; x.u = u; return x.b; }

// float -> bf16 bits, round-to-nearest-even (finite inputs)
__device__ __forceinline__ unsigned short f2b(float x) {
  unsigned int u = __float_as_uint(x);
  unsigned int r = (u + 0x7fffu + ((u >> 16) & 1u)) >> 16;
  return (unsigned short)r;
}
__device__ __forceinline__ float b2f(unsigned int bits_lo16) {
  return __uint_as_float(bits_lo16 << 16);
}

__device__ __forceinline__ float sigm(float x) {
  float e = __builtin_amdgcn_exp2f(x * -1.4426950408889634f);
  return __builtin_amdgcn_rcpf(1.0f + e);
}
__device__ __forceinline__ float tanh_fast(float x) {
  float e = __builtin_amdgcn_exp2f(x * 2.8853900817779268f);
  return 1.0f - 2.0f * __builtin_amdgcn_rcpf(e + 1.0f);
}

// ---------------- prep: build permuted bf16 weight layouts in ws ----------------
// recT [1024 col'][256 k]   : col' = 4u+g  <-> orig col = u + 256g
// kb2  [128 ch][1024 col']  : (kernel + bias) same permutation
// dwT  [128 class][256 k]   : dense_w transposed
__global__ void prep_kernel(const float* __restrict__ rec,
                            const float* __restrict__ kern,
                            const float* __restrict__ bias,
                            const float* __restrict__ dw,
                            unsigned short* __restrict__ recT,
                            unsigned short* __restrict__ kb2,
                            unsigned short* __restrict__ dwT) {
  int id = blockIdx.x * 256 + threadIdx.x;
  if (id < 262144) {                       // 1024*256
    int colp = id >> 8, k = id & 255;
    int u = colp >> 2, g = colp & 3;
    recT[colp * 256 + k] = f2b(rec[k * 1024 + u + 256 * g]);
  } else if (id < 262144 + 131072) {       // 128*1024
    int i = id - 262144;
    int ch = i >> 10, colp = i & 1023;
    int u = colp >> 2, g = colp & 3;
    int oc = u + 256 * g;
    kb2[ch * 1024 + colp] = f2b(kern[ch * 1024 + oc] + bias[oc]);
  } else {                                 // 128*256
    int i = id - 262144 - 131072;
    int cls = i >> 8, k = i & 255;
    dwT[cls * 256 + k] = f2b(dw[k * 128 + cls]);
  }
}

// ---------------- main N-split LSTM kernel ----------------
// Grid 256 = 4 N-splits x 64 batch-groups; block (s = bid>>6, g = bid&63):
//   owns gate-cols' [s*256, s*256+256) = units [s*64, s*64+64) for batch rows
//   [g*16, g*16+16). A slice = 128 KB, FULLY register-resident:
//   8 waves x 2 m-tiles x 64 VGPRs/lane. No A streaming at all.
// Per step: exchange h-slices via L2 (hg double buffer) with device-scope
// release/acquire flags. Safety: a block writes buf[(u+1)&1] only after
// poll(u) proves all siblings finished step u-1 (hence already consumed that
// buffer). Flags/hg zeroed per launch by hipMemsetAsync (replay-safe).
__global__ __launch_bounds__(512)
__attribute__((amdgpu_waves_per_eu(2, 2)))
void lstm_kernel(
    const unsigned short* __restrict__ recT,
    const unsigned short* __restrict__ kb2,
    const unsigned short* __restrict__ dwT,
    const int* __restrict__ x,
    const float* __restrict__ dense_b,
    unsigned short* __restrict__ hg,   // [2][64][16][256] bf16
    int* __restrict__ flags,           // [4][64]
    float* __restrict__ out) {
  __shared__ unsigned short h_cur[16][264];  // padded rows (528 B)
  __shared__ float l_lds[16][132];

  const int tid   = threadIdx.x;
  const int lane  = tid & 63;
  const int wid   = tid >> 6;      // 0..7
  const int row16 = lane & 15;     // batch row within tile
  const int kg    = lane >> 4;     // 0..3
  const int bid   = blockIdx.x;
  const int s     = bid >> 6;      // N-split 0..3
  const int g     = bid & 63;      // batch group
  const int rbase = g << 4;

  // ---- A slice in registers: 2 m-tiles x 8 k-frags = 64 VGPRs ----
  const unsigned short* recBase = recT + ((s * 256 + wid * 32 + row16) * 256 + kg * 8);
  uint4 af[2][8];
#pragma unroll
  for (int m = 0; m < 2; ++m)
#pragma unroll
    for (int k = 0; k < 8; ++k) {
      af[m][k] = *(const uint4*)(recBase + m * 4096 + k * 32);
      asm volatile("" : "+v"(af[m][k].x), "+v"(af[m][k].y),
                        "+v"(af[m][k].z), "+v"(af[m][k].w));
    }

  const int colb = s * 256 + wid * 32;   // this wave's gate-col' base
  const int uu0  = s * 64 + wid * 8 + kg;  // m=0 unit
  const int uu1  = uu0 + 4;                // m=1 unit

  const int* xrow = x + (rbase + row16) * 512;
  int idx_cur = xrow[0];

  float c0 = 0.0f, c1 = 0.0f;

#pragma unroll 1
  for (int u = 0; u < 512; ++u) {
    // kq gather + next-idx prefetch: independent of the exchange, issue first
    const unsigned short* kb = kb2 + (idx_cur * 1024 + colb + kg * 4);
    uint2 kq0 = *(const uint2*)(kb);
    uint2 kq1 = *(const uint2*)(kb + 16);
    int idx_next = xrow[(u + 1 < 512) ? u + 1 : 511];

    // wait for siblings' step-u h (acquire per wave)
#pragma unroll
    for (int j = 0; j < 4; ++j) {
      if (j != s) {
        while (__hip_atomic_load(&flags[j * 64 + g], __ATOMIC_ACQUIRE,
                                 __HIP_MEMORY_SCOPE_AGENT) < u)
          __builtin_amdgcn_s_sleep(1);
      }
    }

    // copy h input (8 KB) global -> LDS (512 threads x 16 B)
    {
      const unsigned short* hsrc = hg + ((u & 1) * 64 + g) * 4096;
      int r = tid >> 5, c = (tid & 31) * 8;
      *(uint4*)&h_cur[r][c] = *(const uint4*)(hsrc + r * 256 + c);
    }
    __syncthreads();

    // GEMM from registers: 2 m-tiles x 8 k
    f32x4 a0 = {0.f, 0.f, 0.f, 0.f}, a1 = {0.f, 0.f, 0.f, 0.f};
#pragma unroll
    for (int k = 0; k < 8; ++k) {
      uint4 hf = *(const uint4*)&h_cur[row16][k * 32 + kg * 8];
      a0 = __builtin_amdgcn_mfma_f32_16x16x32_bf16(as_bf(af[0][k]), as_bf(hf), a0, 0, 0, 0);
      a1 = __builtin_amdgcn_mfma_f32_16x16x32_bf16(as_bf(af[1][k]), as_bf(hf), a1, 0, 0, 0);
    }

    // gates + h-slice write to next buffer
    unsigned short* hdst = hg + (((u + 1) & 1) * 64 + g) * 4096 + row16 * 256;
    {
      float zi = a0[0] + b2f(kq0.x & 0xffffu);
      float zf = a0[1] + b2f(kq0.x >> 16);
      float zg = a0[2] + b2f(kq0.y & 0xffffu);
      float zo = a0[3] + b2f(kq0.y >> 16);
      c0 = sigm(zf) * c0 + sigm(zi) * tanh_fast(zg);
      hdst[uu0] = f2b(sigm(zo) * tanh_fast(c0));
    }
    {
      float zi = a1[0] + b2f(kq1.x & 0xffffu);
      float zf = a1[1] + b2f(kq1.x >> 16);
      float zg = a1[2] + b2f(kq1.y & 0xffffu);
      float zo = a1[3] + b2f(kq1.y >> 16);
      c1 = sigm(zf) * c1 + sigm(zi) * tanh_fast(zg);
      hdst[uu1] = f2b(sigm(zo) * tanh_fast(c1));
    }

    __threadfence();        // drain slice stores to device scope (per wave)
    __syncthreads();        // all waves fenced before the flag
    if (tid == 0)
      __hip_atomic_store(&flags[s * 64 + g], u + 1, __ATOMIC_RELEASE,
                         __HIP_MEMORY_SCOPE_AGENT);
    idx_cur = idx_next;
  }

  // ---- epilogue: split 0 blocks compute dense + softmax for their group ----
  if (s != 0) return;

#pragma unroll
  for (int j = 1; j < 4; ++j) {
    while (__hip_atomic_load(&flags[j * 64 + g], __ATOMIC_ACQUIRE,
                             __HIP_MEMORY_SCOPE_AGENT) < 512)
      __builtin_amdgcn_s_sleep(1);
  }
  {
    const unsigned short* hsrc = hg + (0 * 64 + g) * 4096;  // final h (512 even)
    int r = tid >> 5, c = (tid & 31) * 8;
    *(uint4*)&h_cur[r][c] = *(const uint4*)(hsrc + r * 256 + c);
  }
  __syncthreads();

  {
    const unsigned short* dwBase = dwT + ((wid * 16 + row16) * 256 + kg * 8);
    f32x4 la = {0.f, 0.f, 0.f, 0.f};
#pragma unroll
    for (int k = 0; k < 8; ++k) {
      uint4 hf  = *(const uint4*)&h_cur[row16][k * 32 + kg * 8];
      uint4 afd = *(const uint4*)(dwBase + k * 32);
      la = __builtin_amdgcn_mfma_f32_16x16x32_bf16(as_bf(afd), as_bf(hf), la, 0, 0, 0);
    }
#pragma unroll
    for (int r = 0; r < 4; ++r) {
      int cls = wid * 16 + kg * 4 + r;
      l_lds[row16][cls] = la[r] + dense_b[cls];
    }
  }
  __syncthreads();

  {
    int r = tid >> 5, cg = tid & 31;   // 16 rows x 32 col-groups of 4
    float4 v = *(const float4*)&l_lds[r][cg * 4];
    float mx = fmaxf(fmaxf(v.x, v.y), fmaxf(v.z, v.w));
#pragma unroll
    for (int sh = 1; sh < 32; sh <<= 1) mx = fmaxf(mx, __shfl_xor(mx, sh));
    const float L2E = 1.4426950408889634f;
    float e0 = __builtin_amdgcn_exp2f((v.x - mx) * L2E);
    float e1 = __builtin_amdgcn_exp2f((v.y - mx) * L2E);
    float e2 = __builtin_amdgcn_exp2f((v.z - mx) * L2E);
    float e3 = __builtin_amdgcn_exp2f((v.w - mx) * L2E);
    float sm = e0 + e1 + e2 + e3;
#pragma unroll
    for (int sh = 1; sh < 32; sh <<= 1) sm += __shfl_xor(sm, sh);
    float inv = __builtin_amdgcn_rcpf(sm);
    float4 o = {e0 * inv, e1 * inv, e2 * inv, e3 * inv};
    *(float4*)&out[(rbase + r) * 128 + cg * 4] = o;
  }
}

extern "C" void kernel_launch(void* const* d_in, const int* in_sizes, int n_in,
                              void* d_out, int out_size, void* d_ws, size_t ws_size,
                              hipStream_t stream) {
  const int*   x      = (const int*)d_in[0];    // [1024][512] int32
  const float* kern   = (const float*)d_in[1];  // [128][1024]
  const float* rec    = (const float*)d_in[2];  // [256][1024]
  const float* bias   = (const float*)d_in[3];  // [1024]
  const float* dw     = (const float*)d_in[4];  // [256][128]
  const float* db     = (const float*)d_in[5];  // [128]
  float* outp = (float*)d_out;                  // [1024][128]

  unsigned char* ws = (unsigned char*)d_ws;
  unsigned short* recT = (unsigned short*)(ws);             // 512 KB
  unsigned short* kb2  = (unsigned short*)(ws + 524288);    // 256 KB
  unsigned short* dwT  = (unsigned short*)(ws + 786432);    //  64 KB
  unsigned short* hg   = (unsigned short*)(ws + 851968);    //   1 MB: [2][64][16][256]
  int*            flg  = (int*)(ws + 1900544);              //   1 KB: [4][64]

  prep_kernel<<<1664, 256, 0, stream>>>(rec, kern, bias, dw, recT, kb2, dwT);
  hipMemsetAsync(ws + 851968, 0, 1048576 + 1024, stream);   // zero hg + flags
  lstm_kernel<<<256, 512, 0, stream>>>(recT, kb2, dwT, x, db, hg, flg, outp);
}

// Round 9
// 2784.421 us; speedup vs baseline: 22.4091x; 22.4091x over previous
//
#include <hip/hip_runtime.h>
#include <cstdint>

typedef __bf16 bf16x8 __attribute__((ext_vector_type(8)));
typedef float  f32x4  __attribute__((ext_vector_type(4)));

union U4B { uint4 u; bf16x8 b; };
__device__ __forceinline__ bf16x8 as_bf(uint4 u) { U4B x; x.u = u; return x.b; }

// float -> bf16 bits, round-to-nearest-even (finite inputs)
__device__ __forceinline__ unsigned short f2b(float x) {
  unsigned int u = __float_as_uint(x);
  unsigned int r = (u + 0x7fffu + ((u >> 16) & 1u)) >> 16;
  return (unsigned short)r;
}
__device__ __forceinline__ float b2f(unsigned int bits_lo16) {
  return __uint_as_float(bits_lo16 << 16);
}

__device__ __forceinline__ float sigm(float x) {
  float e = __builtin_amdgcn_exp2f(x * -1.4426950408889634f);
  return __builtin_amdgcn_rcpf(1.0f + e);
}
__device__ __forceinline__ float tanh_fast(float x) {
  float e = __builtin_amdgcn_exp2f(x * 2.8853900817779268f);
  return 1.0f - 2.0f * __builtin_amdgcn_rcpf(e + 1.0f);
}

// ---------------- prep: build permuted bf16 weight layouts in ws ----------------
// recT [1024 col'][256 k]   : col' = 4u+g  <-> orig col = u + 256g
// kb2  [128 ch][1024 col']  : (kernel + bias) same permutation
// dwT  [128 class][256 k]   : dense_w transposed
__global__ void prep_kernel(const float* __restrict__ rec,
                            const float* __restrict__ kern,
                            const float* __restrict__ bias,
                            const float* __restrict__ dw,
                            unsigned short* __restrict__ recT,
                            unsigned short* __restrict__ kb2,
                            unsigned short* __restrict__ dwT) {
  int id = blockIdx.x * 256 + threadIdx.x;
  if (id < 262144) {                       // 1024*256
    int colp = id >> 8, k = id & 255;
    int u = colp >> 2, g = colp & 3;
    recT[colp * 256 + k] = f2b(rec[k * 1024 + u + 256 * g]);
  } else if (id < 262144 + 131072) {       // 128*1024
    int i = id - 262144;
    int ch = i >> 10, colp = i & 1023;
    int u = colp >> 2, g = colp & 3;
    int oc = u + 256 * g;
    kb2[ch * 1024 + colp] = f2b(kern[ch * 1024 + oc] + bias[oc]);
  } else {                                 // 128*256
    int i = id - 262144 - 131072;
    int cls = i >> 8, k = i & 255;
    dwT[cls * 256 + k] = f2b(dw[k * 128 + cls]);
  }
}

// ---------------- main persistent LSTM kernel ----------------
// 64 blocks x 512 threads (8 waves; waves_per_eu(2,2) -> 256-reg unified budget).
// Block owns 16 batch rows for all 512 steps. Wave wid owns gate-cols'
// [wid*128, wid*128+128) = 8 m-tiles:
//   m 0..3 : AGPR-resident (128 accum regs; otherwise-idle capacity)
//   m 4..5 : LDS-resident (128 KB/block, staged once)
//   m 6..7 : streamed, full 8-frag buffers, BURST prefetch >= half-step ahead
// Two half-step groups (A: m0..3, B: m4..7) keep live acc at 16 regs and give
// every VMEM consume >=1000 cyc of issue-to-use distance. kq rotates one full
// step ahead. Nothing in the critical path waits on VMEM.
__global__ __launch_bounds__(512)
__attribute__((amdgpu_waves_per_eu(2, 2)))
void lstm_kernel(
    const unsigned short* __restrict__ recT,
    const unsigned short* __restrict__ kb2,
    const unsigned short* __restrict__ dwT,
    const int* __restrict__ x,
    const float* __restrict__ dense_b,
    float* __restrict__ out) {
  __shared__ uint4 A_lds[2][8][512];            // 128 KB, [slot][k][wid*64+lane]
  __shared__ unsigned short h_buf[2][16][264];  // 16.9 KB bf16 h, padded rows

  const int tid   = threadIdx.x;
  const int lane  = tid & 63;
  const int wid   = tid >> 6;      // 0..7
  const int row16 = lane & 15;     // batch row within tile
  const int kg    = lane >> 4;     // 0..3
  const int rbase = blockIdx.x << 4;

  const unsigned short* recBase = recT + ((wid * 128 + row16) * 256 + kg * 8);

  // ---- m0..3 into AGPRs (128 accum regs), loaded once ----
  uint4 af[4][8];
#pragma unroll
  for (int m = 0; m < 4; ++m)
#pragma unroll
    for (int k = 0; k < 8; ++k) {
      af[m][k] = *(const uint4*)(recBase + m * 4096 + k * 32);
      asm volatile("" : "+a"(af[m][k].x), "+a"(af[m][k].y),
                        "+a"(af[m][k].z), "+a"(af[m][k].w));
    }

  // ---- m4..5 into LDS, staged once ----
#pragma unroll
  for (int s = 0; s < 2; ++s)
#pragma unroll
    for (int k = 0; k < 8; ++k)
      A_lds[s][k][wid * 64 + lane] = *(const uint4*)(recBase + (4 + s) * 4096 + k * 32);

  // ---- m6..7 stream bases + full 8-frag buffers; preload lo frags 0..3 ----
  const unsigned short* sb6 = recBase + 6 * 4096;
  const unsigned short* sb7 = recBase + 7 * 4096;
  uint4 st6[8], st7[8];
#pragma unroll
  for (int k = 0; k < 4; ++k) {
    st6[k] = *(const uint4*)(sb6 + k * 32);
    st7[k] = *(const uint4*)(sb7 + k * 32);
  }

  // zero h(0)
  for (int e = tid; e < 16 * 264; e += 512) (&h_buf[0][0][0])[e] = 0;

  float c_state[8];
#pragma unroll
  for (int m = 0; m < 8; ++m) c_state[m] = 0.0f;

  const int* xrow = x + (rbase + row16) * 512;
  int idx_cur = xrow[0];
  const int colb = wid * 128;

  // preload kq for t=0
  uint2 kq0[4], kq1[4];
  {
    const unsigned short* kb = kb2 + (idx_cur * 1024 + colb + kg * 4);
#pragma unroll
    for (int m = 0; m < 4; ++m) { kq0[m] = *(const uint2*)(kb + m * 16);
                                  kq1[m] = *(const uint2*)(kb + (4 + m) * 16); }
  }

  __syncthreads();

  int cur = 0;
  const unsigned aoff_base = (wid * 64 + lane) * 16;  // byte off in each [s][k] plane

#pragma unroll 1
  for (int t = 0; t < 512; ++t) {
    // launder loop-invariant bases (the reissued stream loads have invariant
    // values; without this LICM folds them away and re-hoists the stream)
    unsigned z6 = 0, zL = 0;
    asm volatile("" : "+v"(z6), "+v"(zL));
    const unsigned short* sb6v = sb6 + z6;
    const unsigned short* sb7v = sb7 + z6;
    const unsigned aoff = aoff_base + zL;

    // BURST 1: hi frags 4..7 for THIS step (consumed after group A, ~1200cyc)
#pragma unroll
    for (int k = 4; k < 8; ++k) {
      st6[k] = *(const uint4*)(sb6v + k * 32);
      st7[k] = *(const uint4*)(sb7v + k * 32);
    }
    int idx_next = xrow[(t + 1 < 512) ? t + 1 : 511];

    const unsigned short* hrow = &h_buf[cur][row16][0];
    unsigned short* hn = &h_buf[cur ^ 1][row16][wid * 32 + kg];

    // ---- group A: m0..3 from AGPRs (no VMEM) ----
    f32x4 a0 = {0,0,0,0}, a1 = {0,0,0,0}, a2 = {0,0,0,0}, a3 = {0,0,0,0};
#pragma unroll
    for (int k = 0; k < 8; ++k) {
      uint4 hf = *(const uint4*)(hrow + k * 32 + kg * 8);
      a0 = __builtin_amdgcn_mfma_f32_16x16x32_bf16(as_bf(af[0][k]), as_bf(hf), a0, 0, 0, 0);
      a1 = __builtin_amdgcn_mfma_f32_16x16x32_bf16(as_bf(af[1][k]), as_bf(hf), a1, 0, 0, 0);
      a2 = __builtin_amdgcn_mfma_f32_16x16x32_bf16(as_bf(af[2][k]), as_bf(hf), a2, 0, 0, 0);
      a3 = __builtin_amdgcn_mfma_f32_16x16x32_bf16(as_bf(af[3][k]), as_bf(hf), a3, 0, 0, 0);
    }
    {
      f32x4 ag[4] = {a0, a1, a2, a3};
#pragma unroll
      for (int m = 0; m < 4; ++m) {
        float zi = ag[m][0] + b2f(kq0[m].x & 0xffffu);
        float zf = ag[m][1] + b2f(kq0[m].x >> 16);
        float zg = ag[m][2] + b2f(kq0[m].y & 0xffffu);
        float zo = ag[m][3] + b2f(kq0[m].y >> 16);
        float c  = sigm(zf) * c_state[m] + sigm(zi) * tanh_fast(zg);
        c_state[m] = c;
        hn[m * 4] = f2b(sigm(zo) * tanh_fast(c));
      }
    }

    // mid: rotate kq0 for t+1 (consumed at next step's gates-A; ~1 step cover)
    const unsigned short* kbn = kb2 + (idx_next * 1024 + colb + kg * 4);
#pragma unroll
    for (int m = 0; m < 4; ++m) kq0[m] = *(const uint2*)(kbn + m * 16);

    // ---- group B: m4..5 (LDS) + m6..7 (streamed) ----
    f32x4 b0 = {0,0,0,0}, b1 = {0,0,0,0}, b2v = {0,0,0,0}, b3 = {0,0,0,0};
#pragma unroll
    for (int k = 0; k < 8; ++k) {
      uint4 hf = *(const uint4*)(hrow + k * 32 + kg * 8);
      uint4 a4 = *(const uint4*)((const char*)A_lds + (0 * 8 + k) * 8192 + aoff);
      uint4 a5 = *(const uint4*)((const char*)A_lds + (1 * 8 + k) * 8192 + aoff);
      b0 = __builtin_amdgcn_mfma_f32_16x16x32_bf16(as_bf(a4), as_bf(hf), b0, 0, 0, 0);
      b1 = __builtin_amdgcn_mfma_f32_16x16x32_bf16(as_bf(a5), as_bf(hf), b1, 0, 0, 0);
      b2v = __builtin_amdgcn_mfma_f32_16x16x32_bf16(as_bf(st6[k]), as_bf(hf), b2v, 0, 0, 0);
      b3 = __builtin_amdgcn_mfma_f32_16x16x32_bf16(as_bf(st7[k]), as_bf(hf), b3, 0, 0, 0);
      if (k < 4) {  // reissue lo frag for t+1 right after consume (~1 step cover)
        st6[k] = *(const uint4*)(sb6v + k * 32);
        st7[k] = *(const uint4*)(sb7v + k * 32);
      }
    }
    {
      f32x4 bg[4] = {b0, b1, b2v, b3};
#pragma unroll
      for (int m = 0; m < 4; ++m) {
        float zi = bg[m][0] + b2f(kq1[m].x & 0xffffu);
        float zf = bg[m][1] + b2f(kq1[m].x >> 16);
        float zg = bg[m][2] + b2f(kq1[m].y & 0xffffu);
        float zo = bg[m][3] + b2f(kq1[m].y >> 16);
        float c  = sigm(zf) * c_state[4 + m] + sigm(zi) * tanh_fast(zg);
        c_state[4 + m] = c;
        hn[(4 + m) * 4] = f2b(sigm(zo) * tanh_fast(c));
      }
    }

    // rotate kq1 for t+1 (consumed at next step's gates-B)
#pragma unroll
    for (int m = 0; m < 4; ++m) kq1[m] = *(const uint2*)(kbn + (4 + m) * 16);

    __syncthreads();
    cur ^= 1;
    idx_cur = idx_next;
  }

  // ---- final dense (MFMA) + softmax; final h is in h_buf[0] (512 steps, even) ----
  float (*l_lds)[132] = (float (*)[132])A_lds;  // overlay logits onto A_lds region
  {
    const unsigned short* dwBase = dwT + ((wid * 16 + row16) * 256 + kg * 8);
    f32x4 la = {0.f, 0.f, 0.f, 0.f};
#pragma unroll
    for (int k = 0; k < 8; ++k) {
      uint4 hf  = *(const uint4*)&h_buf[0][row16][k * 32 + kg * 8];
      uint4 afd = *(const uint4*)(dwBase + k * 32);
      la = __builtin_amdgcn_mfma_f32_16x16x32_bf16(as_bf(afd), as_bf(hf), la, 0, 0, 0);
    }
#pragma unroll
    for (int r = 0; r < 4; ++r) {
      int cls = wid * 16 + kg * 4 + r;
      l_lds[row16][cls] = la[r] + dense_b[cls];
    }
  }
  __syncthreads();

  {
    int r = tid >> 5, cg = tid & 31;   // 16 rows x 32 col-groups of 4
    float4 v = *(const float4*)&l_lds[r][cg * 4];
    float mx = fmaxf(fmaxf(v.x, v.y), fmaxf(v.z, v.w));
#pragma unroll
    for (int sh = 1; sh < 32; sh <<= 1) mx = fmaxf(mx, __shfl_xor(mx, sh));
    const float L2E = 1.4426950408889634f;
    float e0 = __builtin_amdgcn_exp2f((v.x - mx) * L2E);
    float e1 = __builtin_amdgcn_exp2f((v.y - mx) * L2E);
    float e2 = __builtin_amdgcn_exp2f((v.z - mx) * L2E);
    float e3 = __builtin_amdgcn_exp2f((v.w - mx) * L2E);
    float sm = e0 + e1 + e2 + e3;
#pragma unroll
    for (int sh = 1; sh < 32; sh <<= 1) sm += __shfl_xor(sm, sh);
    float inv = __builtin_amdgcn_rcpf(sm);
    float4 o = {e0 * inv, e1 * inv, e2 * inv, e3 * inv};
    *(float4*)&out[(rbase + r) * 128 + cg * 4] = o;
  }
}

extern "C" void kernel_launch(void* const* d_in, const int* in_sizes, int n_in,
                              void* d_out, int out_size, void* d_ws, size_t ws_size,
                              hipStream_t stream) {
  const int*   x      = (const int*)d_in[0];    // [1024][512] int32
  const float* kern   = (const float*)d_in[1];  // [128][1024]
  const float* rec    = (const float*)d_in[2];  // [256][1024]
  const float* bias   = (const float*)d_in[3];  // [1024]
  const float* dw     = (const float*)d_in[4];  // [256][128]
  const float* db     = (const float*)d_in[5];  // [128]
  float* outp = (float*)d_out;                  // [1024][128]

  unsigned char* ws = (unsigned char*)d_ws;
  unsigned short* recT = (unsigned short*)(ws);            // 512 KB
  unsigned short* kb2  = (unsigned short*)(ws + 524288);   // 256 KB
  unsigned short* dwT  = (unsigned short*)(ws + 786432);   //  64 KB

  prep_kernel<<<1664, 256, 0, stream>>>(rec, kern, bias, dw, recT, kb2, dwT);
  lstm_kernel<<<64, 512, 0, stream>>>(recT, kb2, dwT, x, db, outp);
}